// Round 8
// baseline (422.316 us; speedup 1.0000x reference)
//
#include <hip/hip_runtime.h>

#define HD 128   // hidden / feature dim
#define PS 32    // pooling chunks per graph

// ---------------- init: zero in-degree counters ----------------
__global__ __launch_bounds__(256) void k_init(int* cnt, int n) {
  int i = blockIdx.x * 256 + threadIdx.x;
  if (i < n) cnt[i] = 0;
}

// ---------------- in-degree histogram over dst; record per-edge slot ----------------
__global__ __launch_bounds__(256) void k_hist(const int* __restrict__ dst, int* __restrict__ cnt,
                                              int* __restrict__ eslot, int e) {
  int i = blockIdx.x * 256 + threadIdx.x;
  if (i < e) eslot[i] = atomicAdd(&cnt[dst[i]], 1);
}

// ---------------- exclusive scan (2 kernels) ----------------
__global__ __launch_bounds__(256) void k_scan1(const int* __restrict__ cnt, int* __restrict__ excl,
                                               int* __restrict__ bsum, int n) {
  __shared__ int s[256];
  int tid = threadIdx.x;
  int i = blockIdx.x * 256 + tid;
  int v = (i < n) ? cnt[i] : 0;
  s[tid] = v; __syncthreads();
  for (int off = 1; off < 256; off <<= 1) {
    int t = (tid >= off) ? s[tid - off] : 0;
    __syncthreads();
    s[tid] += t;
    __syncthreads();
  }
  if (i < n) excl[i] = s[tid] - v;
  if (tid == 255) bsum[blockIdx.x] = s[255];
}

// scan of block sums + init graph-range sentinels (runs before k_finalize)
__global__ __launch_bounds__(256) void k_scan2(int* __restrict__ bsum, int nb,
                                               int* __restrict__ gstart, int* __restrict__ gend, int g) {
  __shared__ int s[256];
  int tid = threadIdx.x;
  if (tid < g) { gstart[tid] = 0x7fffffff; gend[tid] = -1; }
  int v = (tid < nb) ? bsum[tid] : 0;
  s[tid] = v; __syncthreads();
  for (int off = 1; off < 256; off <<= 1) {
    int t = (tid >= off) ? s[tid - off] : 0;
    __syncthreads();
    s[tid] += t;
    __syncthreads();
  }
  if (tid < nb) bsum[tid] = s[tid] - v;
}

// rowptr += block offset; dis = rsqrt(1+deg_in); graph ranges via sorted-batch
// boundary detection (batch is sorted -> each graph is a contiguous node range)
__global__ __launch_bounds__(256) void k_finalize(int* __restrict__ rowptr, const int* __restrict__ bsum,
                                                  const int* __restrict__ cnt, float* __restrict__ dis,
                                                  const int* __restrict__ batch, int* __restrict__ gstart,
                                                  int* __restrict__ gend, int n) {
  int i = blockIdx.x * 256 + threadIdx.x;
  if (i >= n) return;
  rowptr[i] += bsum[blockIdx.x];
  dis[i] = rsqrtf(1.0f + (float)cnt[i]);
  int b = batch[i];
  if (i == 0 || batch[i - 1] != b) gstart[b] = i;       // plain stores, no atomics
  if (i == n - 1 || batch[i + 1] != b) gend[b] = i;
}

// ---------------- CSR fill (atomic-free): csr[rowptr[dst]+eslot] = src ----------------
__global__ __launch_bounds__(256) void k_fill(const int* __restrict__ src, const int* __restrict__ dst,
                                              const int* __restrict__ rowptr, const int* __restrict__ eslot,
                                              int* __restrict__ csr, int e) {
  int i = blockIdx.x * 256 + threadIdx.x;
  if (i >= e) return;
  csr[rowptr[dst[i]] + eslot[i]] = src[i];
}

// ---------------- fp32 GEMM: C[M x 128] = rowscale[r] * (A[M x 128] @ W[128 x 128]) --------
// BM=128, BN=64, BK=32; 256 threads; micro-tile 8x4; software-pipelined staging:
// tile t+1 is loaded to REGISTERS before computing tile t, LDS-written after —
// the barrier never waits on HBM (breaks the stage->sync vmcnt(0) drain).
#define GBM 128
#define GBN 64
#define GBK 32
__global__ __launch_bounds__(256) void k_gemm(const float* __restrict__ A, const float* __restrict__ W,
                                              const float* __restrict__ rowscale,
                                              float* __restrict__ C, int M) {
  __shared__ float As[GBK][GBM + 4];   // k-major
  __shared__ float Ws[GBK][GBN + 4];
  int tid = threadIdx.x;
  int tx = tid & 15;                   // cols tx*4..+4
  int ty = tid >> 4;                   // rows ty*8..+8
  int row0 = blockIdx.x * GBM;
  int col0 = blockIdx.y * GBN;

  int ar = tid >> 1;                         // A stage: row 0..127
  int akq = (tid & 1) << 4;                  // k-offset 0 or 16 (2 float4 each)
  int wkr = tid >> 4;                        // W stage: k-row 0..15 (x2)
  int wc4 = (tid & 15) << 2;                 // col quad

  float4 ra0, ra1, ra2, ra3, rw0, rw1;
  auto stage_load = [&](int kt) {
    ra0 = ra1 = ra2 = ra3 = make_float4(0.f, 0.f, 0.f, 0.f);
    if (row0 + ar < M) {
      const float* ap = A + (size_t)(row0 + ar) * HD + kt + akq;
      ra0 = *(const float4*)(ap);
      ra1 = *(const float4*)(ap + 4);
      ra2 = *(const float4*)(ap + 8);
      ra3 = *(const float4*)(ap + 12);
    }
    const float* wp = W + (size_t)(kt + wkr) * HD + col0 + wc4;
    rw0 = *(const float4*)(wp);
    rw1 = *(const float4*)(wp + 16 * HD);
  };
  auto stage_store = [&]() {
    As[akq + 0][ar] = ra0.x; As[akq + 1][ar] = ra0.y; As[akq + 2][ar] = ra0.z; As[akq + 3][ar] = ra0.w;
    As[akq + 4][ar] = ra1.x; As[akq + 5][ar] = ra1.y; As[akq + 6][ar] = ra1.z; As[akq + 7][ar] = ra1.w;
    As[akq + 8][ar] = ra2.x; As[akq + 9][ar] = ra2.y; As[akq + 10][ar] = ra2.z; As[akq + 11][ar] = ra2.w;
    As[akq + 12][ar] = ra3.x; As[akq + 13][ar] = ra3.y; As[akq + 14][ar] = ra3.z; As[akq + 15][ar] = ra3.w;
    *(float4*)(&Ws[wkr][wc4]) = rw0;
    *(float4*)(&Ws[wkr + 16][wc4]) = rw1;
  };

  float acc[8][4];
#pragma unroll
  for (int i = 0; i < 8; ++i)
#pragma unroll
    for (int j = 0; j < 4; ++j) acc[i][j] = 0.f;

  stage_load(0);
  stage_store();
  __syncthreads();

  for (int t = 0; t < HD / GBK; ++t) {
    if (t + 1 < HD / GBK) stage_load((t + 1) * GBK);   // loads in flight during compute
#pragma unroll
    for (int kk = 0; kk < GBK; ++kk) {
      float4 b = *(const float4*)(&Ws[kk][tx * 4]);
      float4 alo = *(const float4*)(&As[kk][ty * 8]);
      float4 ahi = *(const float4*)(&As[kk][ty * 8 + 4]);
      float ar8[8] = {alo.x, alo.y, alo.z, alo.w, ahi.x, ahi.y, ahi.z, ahi.w};
#pragma unroll
      for (int i = 0; i < 8; ++i) {
        acc[i][0] += ar8[i] * b.x; acc[i][1] += ar8[i] * b.y;
        acc[i][2] += ar8[i] * b.z; acc[i][3] += ar8[i] * b.w;
      }
    }
    if (t + 1 < HD / GBK) {
      __syncthreads();
      stage_store();
      __syncthreads();
    }
  }
#pragma unroll
  for (int i = 0; i < 8; ++i) {
    int r = row0 + ty * 8 + i;
    if (r < M) {
      float sc = rowscale[r];
      *(float4*)(C + (size_t)r * HD + col0 + tx * 4) =
          make_float4(sc * acc[i][0], sc * acc[i][1], sc * acc[i][2], sc * acc[i][3]);
    }
  }
}

// ---------------- gather aggregation + self loop + bias + relu ----------------
// C rows are pre-scaled by dis[row]. out = relu(dn*(sum C[src] + C[node]) + b).
// One wave per node; half-wave 0 (lanes 0-31) takes even edge slots, half 1 odd.
__global__ __launch_bounds__(256) void k_gather(const float* __restrict__ C, const float* __restrict__ dis,
                                                const int* __restrict__ rowptr, const int* __restrict__ cnt,
                                                const int* __restrict__ csr, const float* __restrict__ bias,
                                                float* __restrict__ out, int n) {
  int lane = threadIdx.x & 63;
  int wid = threadIdx.x >> 6;
  int node = blockIdx.x * 4 + wid;
  if (node >= n) return;
  int half = lane >> 5;          // 0 or 1
  int l32 = lane & 31;
  int coff = l32 * 4;            // this lane's 4 channels
  int s = rowptr[node];
  int deg = cnt[node];

  float dn = dis[node];
  float4 selfv = *(const float4*)(C + (size_t)node * HD + coff);
  float4 bb = *(const float4*)(bias + coff);

  float4 a0 = make_float4(0.f, 0.f, 0.f, 0.f);
  float4 a1 = make_float4(0.f, 0.f, 0.f, 0.f);
  int i = 0;
  for (; i + 4 <= deg; i += 4) {           // 4 edges/iter: half h takes slots i+h, i+2+h
    int i0 = csr[s + i + half];
    int i1 = csr[s + i + 2 + half];
    float4 v0 = *(const float4*)(C + (size_t)i0 * HD + coff);
    float4 v1 = *(const float4*)(C + (size_t)i1 * HD + coff);
    a0.x += v0.x; a0.y += v0.y; a0.z += v0.z; a0.w += v0.w;
    a1.x += v1.x; a1.y += v1.y; a1.z += v1.z; a1.w += v1.w;
  }
  if (i + 2 <= deg) {                      // 2 edges: half h takes slot i+h
    int i0 = csr[s + i + half];
    float4 v0 = *(const float4*)(C + (size_t)i0 * HD + coff);
    a0.x += v0.x; a0.y += v0.y; a0.z += v0.z; a0.w += v0.w;
    i += 2;
  }
  if (i < deg && half == 0) {              // last edge: half 0 only
    int i0 = csr[s + i];
    float4 v0 = *(const float4*)(C + (size_t)i0 * HD + coff);
    a0.x += v0.x; a0.y += v0.y; a0.z += v0.z; a0.w += v0.w;
  }
  a0.x += a1.x; a0.y += a1.y; a0.z += a1.z; a0.w += a1.w;
  // combine the two half-wave partials (lane <-> lane^32)
  a0.x += __shfl_xor(a0.x, 32);
  a0.y += __shfl_xor(a0.y, 32);
  a0.z += __shfl_xor(a0.z, 32);
  a0.w += __shfl_xor(a0.w, 32);

  if (half == 0) {
    float4 r;
    r.x = fmaxf(dn * (a0.x + selfv.x) + bb.x, 0.f);
    r.y = fmaxf(dn * (a0.y + selfv.y) + bb.y, 0.f);
    r.z = fmaxf(dn * (a0.z + selfv.z) + bb.z, 0.f);
    r.w = fmaxf(dn * (a0.w + selfv.w) + bb.w, 0.f);
    *(float4*)(out + (size_t)node * HD + coff) = r;
  }
}

// ---------------- pooling stage 1: per-(graph, chunk) partial sum+max ----------------
__global__ __launch_bounds__(128) void k_pool1(const float* __restrict__ h, const int* __restrict__ gstart,
                                               const int* __restrict__ gend, float* __restrict__ psum,
                                               float* __restrict__ pmax) {
  int g = blockIdx.x, sidx = blockIdx.y, c = threadIdx.x;
  int s = gstart[g], e = gend[g];
  float sum = 0.f, mx = 0.f;        // h >= 0 post-ReLU, so 0 is a safe max identity
  if (s <= e) {
    int len = e - s + 1;
    int c0 = s + (int)(((long long)len * sidx) / PS);
    int c1 = s + (int)(((long long)len * (sidx + 1)) / PS);
    for (int i = c0; i < c1; ++i) {
      float v = h[(size_t)i * HD + c];
      sum += v;
      mx = fmaxf(mx, v);
    }
  }
  size_t o = ((size_t)g * PS + sidx) * HD + c;
  psum[o] = sum;
  pmax[o] = mx;
}

// ---------------- pooling stage 2 fused with MLP ----------------
__global__ __launch_bounds__(128) void k_pool2mlp(const float* __restrict__ psum, const float* __restrict__ pmax,
                                                  const int* __restrict__ gstart, const int* __restrict__ gend,
                                                  const float* __restrict__ Wf1, const float* __restrict__ bf1,
                                                  const float* __restrict__ Wf2, const float* __restrict__ bf2,
                                                  float* __restrict__ out) {
  __shared__ float p[256];
  __shared__ float red[128];
  int g = blockIdx.x, t = threadIdx.x;
  float sum = 0.f, mx = 0.f;
  for (int sidx = 0; sidx < PS; ++sidx) {
    size_t o = ((size_t)g * PS + sidx) * HD + t;
    sum += psum[o];
    mx = fmaxf(mx, pmax[o]);
  }
  int s = gstart[g], e = gend[g];
  float cntf = (s <= e) ? (float)(e - s + 1) : 1.0f;
  p[t] = sum / cntf;
  p[t + 128] = mx;
  __syncthreads();
  float acc = bf1[t];
  for (int k = 0; k < 256; ++k) acc += p[k] * Wf1[k * HD + t];
  float hv = fmaxf(acc, 0.f);
  red[t] = hv * Wf2[t];
  __syncthreads();
  for (int off = 64; off > 0; off >>= 1) {
    if (t < off) red[t] += red[t + off];
    __syncthreads();
  }
  if (t == 0) out[g] = red[0] + bf2[0];
}

extern "C" void kernel_launch(void* const* d_in, const int* in_sizes, int n_in,
                              void* d_out, int out_size, void* d_ws, size_t ws_size,
                              hipStream_t stream) {
  const float* x   = (const float*)d_in[0];
  const int*   ei  = (const int*)d_in[1];
  const int*   bat = (const int*)d_in[2];
  const float* W1  = (const float*)d_in[3];
  const float* b1  = (const float*)d_in[4];
  const float* W2  = (const float*)d_in[5];
  const float* b2  = (const float*)d_in[6];
  const float* W3  = (const float*)d_in[7];
  const float* b3  = (const float*)d_in[8];
  const float* Wf1 = (const float*)d_in[9];
  const float* bf1 = (const float*)d_in[10];
  const float* Wf2 = (const float*)d_in[11];
  const float* bf2 = (const float*)d_in[12];

  int N = in_sizes[0] / HD;
  int E = in_sizes[1] / 2;
  int G = out_size;

  char* w = (char*)d_ws;
  size_t off = 0;
  auto alloc = [&](size_t bytes) -> void* {
    void* p = w + off;
    off = (off + bytes + 255) & ~(size_t)255;
    return p;
  };
  float* bufA   = (float*)alloc((size_t)N * HD * 4);
  float* bufB   = (float*)alloc((size_t)N * HD * 4);
  int*   csr    = (int*)alloc((size_t)E * 4);
  int*   cnt    = (int*)alloc((size_t)N * 4);
  int*   rowptr = (int*)alloc((size_t)N * 4);
  float* dis    = (float*)alloc((size_t)N * 4);
  int*   bsum   = (int*)alloc(256 * 4);
  int*   gstart = (int*)alloc((size_t)G * 4);
  int*   gend   = (int*)alloc((size_t)G * 4);
  float* psum   = (float*)alloc((size_t)G * PS * HD * 4);
  float* pmax   = (float*)alloc((size_t)G * PS * HD * 4);
  int*   eslot  = (int*)bufA;   // alias: eslot dead before first gemm writes bufA

  int nbN = (N + 255) / 256;
  int nbE = (E + 255) / 256;

  k_init<<<nbN, 256, 0, stream>>>(cnt, N);
  k_hist<<<nbE, 256, 0, stream>>>(ei + E, cnt, eslot, E);
  k_scan1<<<nbN, 256, 0, stream>>>(cnt, rowptr, bsum, N);
  k_scan2<<<1, 256, 0, stream>>>(bsum, nbN, gstart, gend, G);
  k_finalize<<<nbN, 256, 0, stream>>>(rowptr, bsum, cnt, dis, bat, gstart, gend, N);
  k_fill<<<nbE, 256, 0, stream>>>(ei, ei + E, rowptr, eslot, csr, E);

  dim3 ggrid((N + GBM - 1) / GBM, HD / GBN);
  int ab = (N + 3) / 4;
  k_gemm<<<ggrid, 256, 0, stream>>>(x, W1, dis, bufA, N);
  k_gather<<<ab, 256, 0, stream>>>(bufA, dis, rowptr, cnt, csr, b1, bufB, N);
  k_gemm<<<ggrid, 256, 0, stream>>>(bufB, W2, dis, bufA, N);
  k_gather<<<ab, 256, 0, stream>>>(bufA, dis, rowptr, cnt, csr, b2, bufB, N);
  k_gemm<<<ggrid, 256, 0, stream>>>(bufB, W3, dis, bufA, N);
  k_gather<<<ab, 256, 0, stream>>>(bufA, dis, rowptr, cnt, csr, b3, bufB, N);

  dim3 pgrid(G, PS);
  k_pool1<<<pgrid, 128, 0, stream>>>(bufB, gstart, gend, psum, pmax);
  k_pool2mlp<<<G, 128, 0, stream>>>(psum, pmax, gstart, gend, Wf1, bf1, Wf2, bf2, (float*)d_out);
}

// Round 9
// 353.205 us; speedup vs baseline: 1.1957x; 1.1957x over previous
//
#include <hip/hip_runtime.h>

#define HD 128   // hidden / feature dim
#define PS 32    // pooling chunks per graph

typedef __bf16 bf16x8 __attribute__((ext_vector_type(8)));
typedef float  f32x16 __attribute__((ext_vector_type(16)));
typedef unsigned short u16x4 __attribute__((ext_vector_type(4)));

__device__ inline unsigned short f2bf_rne(float f) {
  unsigned u = __builtin_bit_cast(unsigned, f);
  unsigned r = u + 0x7fffu + ((u >> 16) & 1u);
  return (unsigned short)(r >> 16);
}
__device__ inline float bf2f(unsigned short h) {
  unsigned u = ((unsigned)h) << 16;
  return __builtin_bit_cast(float, u);
}
__device__ inline void cvt4(float4 f, u16x4& h, u16x4& l) {
  h[0] = f2bf_rne(f.x); l[0] = f2bf_rne(f.x - bf2f(h[0]));
  h[1] = f2bf_rne(f.y); l[1] = f2bf_rne(f.y - bf2f(h[1]));
  h[2] = f2bf_rne(f.z); l[2] = f2bf_rne(f.z - bf2f(h[2]));
  h[3] = f2bf_rne(f.w); l[3] = f2bf_rne(f.w - bf2f(h[3]));
}

// ---------------- init: zero in-degree counters ----------------
__global__ __launch_bounds__(256) void k_init(int* cnt, int n) {
  int i = blockIdx.x * 256 + threadIdx.x;
  if (i < n) cnt[i] = 0;
}

// ---------------- in-degree histogram over dst; record per-edge slot ----------------
__global__ __launch_bounds__(256) void k_hist(const int* __restrict__ dst, int* __restrict__ cnt,
                                              int* __restrict__ eslot, int e) {
  int i = blockIdx.x * 256 + threadIdx.x;
  if (i < e) eslot[i] = atomicAdd(&cnt[dst[i]], 1);
}

// ---------------- exclusive scan ----------------
__global__ __launch_bounds__(256) void k_scan1(const int* __restrict__ cnt, int* __restrict__ excl,
                                               int* __restrict__ bsum, int n) {
  __shared__ int s[256];
  int tid = threadIdx.x;
  int i = blockIdx.x * 256 + tid;
  int v = (i < n) ? cnt[i] : 0;
  s[tid] = v; __syncthreads();
  for (int off = 1; off < 256; off <<= 1) {
    int t = (tid >= off) ? s[tid - off] : 0;
    __syncthreads();
    s[tid] += t;
    __syncthreads();
  }
  if (i < n) excl[i] = s[tid] - v;
  if (tid == 255) bsum[blockIdx.x] = s[255];
}

__global__ __launch_bounds__(256) void k_scan2(int* __restrict__ bsum, int nb,
                                               int* __restrict__ gstart, int* __restrict__ gend, int g) {
  __shared__ int s[256];
  int tid = threadIdx.x;
  if (tid < g) { gstart[tid] = 0x7fffffff; gend[tid] = -1; }
  int v = (tid < nb) ? bsum[tid] : 0;
  s[tid] = v; __syncthreads();
  for (int off = 1; off < 256; off <<= 1) {
    int t = (tid >= off) ? s[tid - off] : 0;
    __syncthreads();
    s[tid] += t;
    __syncthreads();
  }
  if (tid < nb) bsum[tid] = s[tid] - v;
}

// rowptr += block offset; dis = rsqrt(1+deg); graph ranges via sorted-batch boundaries
__global__ __launch_bounds__(256) void k_finalize(int* __restrict__ rowptr, const int* __restrict__ bsum,
                                                  const int* __restrict__ cnt, float* __restrict__ dis,
                                                  const int* __restrict__ batch, int* __restrict__ gstart,
                                                  int* __restrict__ gend, int n) {
  int i = blockIdx.x * 256 + threadIdx.x;
  if (i >= n) return;
  rowptr[i] += bsum[blockIdx.x];
  dis[i] = rsqrtf(1.0f + (float)cnt[i]);
  int b = batch[i];
  if (i == 0 || batch[i - 1] != b) gstart[b] = i;
  if (i == n - 1 || batch[i + 1] != b) gend[b] = i;
}

// ---------------- CSR fill (atomic-free) ----------------
__global__ __launch_bounds__(256) void k_fill(const int* __restrict__ src, const int* __restrict__ dst,
                                              const int* __restrict__ rowptr, const int* __restrict__ eslot,
                                              int* __restrict__ csr, int e) {
  int i = blockIdx.x * 256 + threadIdx.x;
  if (i >= e) return;
  csr[rowptr[dst[i]] + eslot[i]] = src[i];
}

// ---------------- W split/transpose/pad: build per-layer LDS image ----------------
// image layout (ushort): [hl][s][c][j]  j:40 (32 k + 8 pad), c:128 cols, s:4 ktiles, hl: hi/lo
// element = bf-split of W[s*32 + j][c]. Per-layer size 2*4*128*40 = 40960 ushorts.
__global__ __launch_bounds__(256) void k_wsplit(const float* __restrict__ W1, const float* __restrict__ W2,
                                                const float* __restrict__ W3, unsigned short* __restrict__ wimg) {
  const float* W = (blockIdx.x == 0) ? W1 : (blockIdx.x == 1) ? W2 : W3;
  unsigned short* out = wimg + (size_t)blockIdx.x * 40960;
  int t = threadIdx.x;
  int c = t & 127;
  int j0 = (t >> 7) * 20;
  for (int s = 0; s < 4; ++s) {
    for (int jj = 0; jj < 20; ++jj) {
      int j = j0 + jj;
      float v = (j < 32) ? W[(size_t)(s * 32 + j) * HD + c] : 0.f;
      unsigned short hi = f2bf_rne(v);
      float lo = (j < 32) ? (v - bf2f(hi)) : 0.f;
      out[(size_t)(s * 128 + c) * 40 + j] = hi;
      out[20480 + (size_t)(s * 128 + c) * 40 + j] = f2bf_rne(lo);
    }
  }
}

// ---------------- split-bf16 MFMA GEMM: C = rowscale[r] * (A @ W) ----------------
// 128 rows x 128 cols per block; 4 waves of 64x64; mfma_f32_32x32x16_bf16;
// C = ah@wh + ah@wl + al@wh accumulated in fp32 (al@wl ~2^-16, dropped).
__global__ __launch_bounds__(256) void k_gemm(const float* __restrict__ A, const unsigned short* __restrict__ wimg_l,
                                              const float* __restrict__ rowscale,
                                              float* __restrict__ C, int M) {
  __shared__ unsigned short alds[2][128][40];   // [hl][r][j], row stride 80B
  __shared__ unsigned short wlds[2][128][40];   // [hl][c][j]
  int t = threadIdx.x;
  int row0 = blockIdx.x * 128;
  int wave = t >> 6;
  int lane = t & 63;
  int wr = (wave & 1) * 64;      // wave row offset
  int wc = (wave >> 1) * 64;     // wave col offset
  int l31 = lane & 31;
  int lhi = lane >> 5;

  f32x16 acc00, acc01, acc10, acc11;
#pragma unroll
  for (int i = 0; i < 16; ++i) { acc00[i] = 0.f; acc01[i] = 0.f; acc10[i] = 0.f; acc11[i] = 0.f; }

  int sr = t >> 1;               // staging row 0..127
  int sh = t & 1;                // k half (16 fp32)

  for (int s = 0; s < 4; ++s) {
    __syncthreads();             // previous compute done before overwrite
    // stage W: linear copy of this ktile's image section (2 x 2560 dwords)
    {
      const uint* s0 = (const uint*)(wimg_l + (size_t)s * 5120);
      const uint* s1 = (const uint*)(wimg_l + 20480 + (size_t)s * 5120);
      uint* d = (uint*)wlds;
#pragma unroll
      for (int q = 0; q < 10; ++q) d[q * 256 + t] = s0[q * 256 + t];
#pragma unroll
      for (int q = 0; q < 10; ++q) d[2560 + q * 256 + t] = s1[q * 256 + t];
    }
    // stage A: 128 rows x 32 k fp32 -> split bf16
    {
      int gr = row0 + sr;
      float4 f0 = make_float4(0.f, 0.f, 0.f, 0.f), f1 = f0, f2 = f0, f3 = f0;
      if (gr < M) {
        const float* ap = A + (size_t)gr * HD + s * 32 + sh * 16;
        f0 = *(const float4*)(ap);
        f1 = *(const float4*)(ap + 4);
        f2 = *(const float4*)(ap + 8);
        f3 = *(const float4*)(ap + 12);
      }
      char* ab = (char*)alds;
      int base = sr * 80 + sh * 32;
      u16x4 h, l;
      cvt4(f0, h, l); *(u16x4*)(ab + base)          = h; *(u16x4*)(ab + 10240 + base)      = l;
      cvt4(f1, h, l); *(u16x4*)(ab + base + 8)      = h; *(u16x4*)(ab + 10240 + base + 8)  = l;
      cvt4(f2, h, l); *(u16x4*)(ab + base + 16)     = h; *(u16x4*)(ab + 10240 + base + 16) = l;
      cvt4(f3, h, l); *(u16x4*)(ab + base + 24)     = h; *(u16x4*)(ab + 10240 + base + 24) = l;
    }
    __syncthreads();
#pragma unroll
    for (int ks = 0; ks < 2; ++ks) {
      int koff = ks * 32 + lhi * 16;   // byte offset within 80B row
      const char* ab = (const char*)alds;
      const char* wb = (const char*)wlds;
      bf16x8 ah0 = *(const bf16x8*)(ab + (wr + l31) * 80 + koff);
      bf16x8 ah1 = *(const bf16x8*)(ab + (wr + 32 + l31) * 80 + koff);
      bf16x8 al0 = *(const bf16x8*)(ab + 10240 + (wr + l31) * 80 + koff);
      bf16x8 al1 = *(const bf16x8*)(ab + 10240 + (wr + 32 + l31) * 80 + koff);
      bf16x8 bh0 = *(const bf16x8*)(wb + (wc + l31) * 80 + koff);
      bf16x8 bh1 = *(const bf16x8*)(wb + (wc + 32 + l31) * 80 + koff);
      bf16x8 bl0 = *(const bf16x8*)(wb + 10240 + (wc + l31) * 80 + koff);
      bf16x8 bl1 = *(const bf16x8*)(wb + 10240 + (wc + 32 + l31) * 80 + koff);

      acc00 = __builtin_amdgcn_mfma_f32_32x32x16_bf16(ah0, bh0, acc00, 0, 0, 0);
      acc00 = __builtin_amdgcn_mfma_f32_32x32x16_bf16(ah0, bl0, acc00, 0, 0, 0);
      acc00 = __builtin_amdgcn_mfma_f32_32x32x16_bf16(al0, bh0, acc00, 0, 0, 0);

      acc01 = __builtin_amdgcn_mfma_f32_32x32x16_bf16(ah0, bh1, acc01, 0, 0, 0);
      acc01 = __builtin_amdgcn_mfma_f32_32x32x16_bf16(ah0, bl1, acc01, 0, 0, 0);
      acc01 = __builtin_amdgcn_mfma_f32_32x32x16_bf16(al0, bh1, acc01, 0, 0, 0);

      acc10 = __builtin_amdgcn_mfma_f32_32x32x16_bf16(ah1, bh0, acc10, 0, 0, 0);
      acc10 = __builtin_amdgcn_mfma_f32_32x32x16_bf16(ah1, bl0, acc10, 0, 0, 0);
      acc10 = __builtin_amdgcn_mfma_f32_32x32x16_bf16(al1, bh0, acc10, 0, 0, 0);

      acc11 = __builtin_amdgcn_mfma_f32_32x32x16_bf16(ah1, bh1, acc11, 0, 0, 0);
      acc11 = __builtin_amdgcn_mfma_f32_32x32x16_bf16(ah1, bl1, acc11, 0, 0, 0);
      acc11 = __builtin_amdgcn_mfma_f32_32x32x16_bf16(al1, bh1, acc11, 0, 0, 0);
    }
  }
  // epilogue: C/D layout col = lane&31, row = (r&3) + 8*(r>>2) + 4*lhi
#pragma unroll
  for (int rt = 0; rt < 2; ++rt) {
#pragma unroll
    for (int ct = 0; ct < 2; ++ct) {
      const f32x16& a = (rt == 0) ? (ct == 0 ? acc00 : acc01) : (ct == 0 ? acc10 : acc11);
      int col = wc + ct * 32 + l31;
      int rbase = row0 + wr + rt * 32 + 4 * lhi;
#pragma unroll
      for (int r = 0; r < 16; ++r) {
        int row = rbase + (r & 3) + 8 * (r >> 2);
        if (row < M) C[(size_t)row * HD + col] = rowscale[row] * a[r];
      }
    }
  }
}

// ---------------- gather aggregation + self loop + bias + relu ----------------
__global__ __launch_bounds__(256) void k_gather(const float* __restrict__ C, const float* __restrict__ dis,
                                                const int* __restrict__ rowptr, const int* __restrict__ cnt,
                                                const int* __restrict__ csr, const float* __restrict__ bias,
                                                float* __restrict__ out, int n) {
  int lane = threadIdx.x & 63;
  int wid = threadIdx.x >> 6;
  int node = blockIdx.x * 4 + wid;
  if (node >= n) return;
  int half = lane >> 5;
  int l32 = lane & 31;
  int coff = l32 * 4;
  int s = rowptr[node];
  int deg = cnt[node];

  float dn = dis[node];
  float4 selfv = *(const float4*)(C + (size_t)node * HD + coff);
  float4 bb = *(const float4*)(bias + coff);

  float4 a0 = make_float4(0.f, 0.f, 0.f, 0.f);
  float4 a1 = make_float4(0.f, 0.f, 0.f, 0.f);
  int i = 0;
  for (; i + 4 <= deg; i += 4) {
    int i0 = csr[s + i + half];
    int i1 = csr[s + i + 2 + half];
    float4 v0 = *(const float4*)(C + (size_t)i0 * HD + coff);
    float4 v1 = *(const float4*)(C + (size_t)i1 * HD + coff);
    a0.x += v0.x; a0.y += v0.y; a0.z += v0.z; a0.w += v0.w;
    a1.x += v1.x; a1.y += v1.y; a1.z += v1.z; a1.w += v1.w;
  }
  if (i + 2 <= deg) {
    int i0 = csr[s + i + half];
    float4 v0 = *(const float4*)(C + (size_t)i0 * HD + coff);
    a0.x += v0.x; a0.y += v0.y; a0.z += v0.z; a0.w += v0.w;
    i += 2;
  }
  if (i < deg && half == 0) {
    int i0 = csr[s + i];
    float4 v0 = *(const float4*)(C + (size_t)i0 * HD + coff);
    a0.x += v0.x; a0.y += v0.y; a0.z += v0.z; a0.w += v0.w;
  }
  a0.x += a1.x; a0.y += a1.y; a0.z += a1.z; a0.w += a1.w;
  a0.x += __shfl_xor(a0.x, 32);
  a0.y += __shfl_xor(a0.y, 32);
  a0.z += __shfl_xor(a0.z, 32);
  a0.w += __shfl_xor(a0.w, 32);

  if (half == 0) {
    float4 r;
    r.x = fmaxf(dn * (a0.x + selfv.x) + bb.x, 0.f);
    r.y = fmaxf(dn * (a0.y + selfv.y) + bb.y, 0.f);
    r.z = fmaxf(dn * (a0.z + selfv.z) + bb.z, 0.f);
    r.w = fmaxf(dn * (a0.w + selfv.w) + bb.w, 0.f);
    *(float4*)(out + (size_t)node * HD + coff) = r;
  }
}

// ---------------- pooling stage 1 ----------------
__global__ __launch_bounds__(128) void k_pool1(const float* __restrict__ h, const int* __restrict__ gstart,
                                               const int* __restrict__ gend, float* __restrict__ psum,
                                               float* __restrict__ pmax) {
  int g = blockIdx.x, sidx = blockIdx.y, c = threadIdx.x;
  int s = gstart[g], e = gend[g];
  float sum = 0.f, mx = 0.f;
  if (s <= e) {
    int len = e - s + 1;
    int c0 = s + (int)(((long long)len * sidx) / PS);
    int c1 = s + (int)(((long long)len * (sidx + 1)) / PS);
    for (int i = c0; i < c1; ++i) {
      float v = h[(size_t)i * HD + c];
      sum += v;
      mx = fmaxf(mx, v);
    }
  }
  size_t o = ((size_t)g * PS + sidx) * HD + c;
  psum[o] = sum;
  pmax[o] = mx;
}

// ---------------- pooling stage 2 fused with MLP ----------------
__global__ __launch_bounds__(128) void k_pool2mlp(const float* __restrict__ psum, const float* __restrict__ pmax,
                                                  const int* __restrict__ gstart, const int* __restrict__ gend,
                                                  const float* __restrict__ Wf1, const float* __restrict__ bf1,
                                                  const float* __restrict__ Wf2, const float* __restrict__ bf2,
                                                  float* __restrict__ out) {
  __shared__ float p[256];
  __shared__ float red[128];
  int g = blockIdx.x, t = threadIdx.x;
  float sum = 0.f, mx = 0.f;
  for (int sidx = 0; sidx < PS; ++sidx) {
    size_t o = ((size_t)g * PS + sidx) * HD + t;
    sum += psum[o];
    mx = fmaxf(mx, pmax[o]);
  }
  int s = gstart[g], e = gend[g];
  float cntf = (s <= e) ? (float)(e - s + 1) : 1.0f;
  p[t] = sum / cntf;
  p[t + 128] = mx;
  __syncthreads();
  float acc = bf1[t];
  for (int k = 0; k < 256; ++k) acc += p[k] * Wf1[k * HD + t];
  float hv = fmaxf(acc, 0.f);
  red[t] = hv * Wf2[t];
  __syncthreads();
  for (int off = 64; off > 0; off >>= 1) {
    if (t < off) red[t] += red[t + off];
    __syncthreads();
  }
  if (t == 0) out[g] = red[0] + bf2[0];
}

extern "C" void kernel_launch(void* const* d_in, const int* in_sizes, int n_in,
                              void* d_out, int out_size, void* d_ws, size_t ws_size,
                              hipStream_t stream) {
  const float* x   = (const float*)d_in[0];
  const int*   ei  = (const int*)d_in[1];
  const int*   bat = (const int*)d_in[2];
  const float* W1  = (const float*)d_in[3];
  const float* b1  = (const float*)d_in[4];
  const float* W2  = (const float*)d_in[5];
  const float* b2  = (const float*)d_in[6];
  const float* W3  = (const float*)d_in[7];
  const float* b3  = (const float*)d_in[8];
  const float* Wf1 = (const float*)d_in[9];
  const float* bf1 = (const float*)d_in[10];
  const float* Wf2 = (const float*)d_in[11];
  const float* bf2 = (const float*)d_in[12];

  int N = in_sizes[0] / HD;
  int E = in_sizes[1] / 2;
  int G = out_size;

  char* w = (char*)d_ws;
  size_t off = 0;
  auto alloc = [&](size_t bytes) -> void* {
    void* p = w + off;
    off = (off + bytes + 255) & ~(size_t)255;
    return p;
  };
  float* bufA   = (float*)alloc((size_t)N * HD * 4);
  float* bufB   = (float*)alloc((size_t)N * HD * 4);
  int*   csr    = (int*)alloc((size_t)E * 4);
  int*   cnt    = (int*)alloc((size_t)N * 4);
  int*   rowptr = (int*)alloc((size_t)N * 4);
  float* dis    = (float*)alloc((size_t)N * 4);
  int*   bsum   = (int*)alloc(256 * 4);
  int*   gstart = (int*)alloc((size_t)G * 4);
  int*   gend   = (int*)alloc((size_t)G * 4);
  float* psum   = (float*)alloc((size_t)G * PS * HD * 4);
  float* pmax   = (float*)alloc((size_t)G * PS * HD * 4);
  unsigned short* wimg = (unsigned short*)alloc((size_t)3 * 40960 * 2);
  int*   eslot  = (int*)bufA;   // alias: eslot dead before first gemm writes bufA

  int nbN = (N + 255) / 256;
  int nbE = (E + 255) / 256;

  k_wsplit<<<3, 256, 0, stream>>>(W1, W2, W3, wimg);
  k_init<<<nbN, 256, 0, stream>>>(cnt, N);
  k_hist<<<nbE, 256, 0, stream>>>(ei + E, cnt, eslot, E);
  k_scan1<<<nbN, 256, 0, stream>>>(cnt, rowptr, bsum, N);
  k_scan2<<<1, 256, 0, stream>>>(bsum, nbN, gstart, gend, G);
  k_finalize<<<nbN, 256, 0, stream>>>(rowptr, bsum, cnt, dis, bat, gstart, gend, N);
  k_fill<<<nbE, 256, 0, stream>>>(ei, ei + E, rowptr, eslot, csr, E);

  int gb = (N + 127) / 128;
  int ab = (N + 3) / 4;
  k_gemm<<<gb, 256, 0, stream>>>(x, wimg, dis, bufA, N);
  k_gather<<<ab, 256, 0, stream>>>(bufA, dis, rowptr, cnt, csr, b1, bufB, N);
  k_gemm<<<gb, 256, 0, stream>>>(bufB, wimg + 40960, dis, bufA, N);
  k_gather<<<ab, 256, 0, stream>>>(bufA, dis, rowptr, cnt, csr, b2, bufB, N);
  k_gemm<<<gb, 256, 0, stream>>>(bufB, wimg + 81920, dis, bufA, N);
  k_gather<<<ab, 256, 0, stream>>>(bufA, dis, rowptr, cnt, csr, b3, bufB, N);

  dim3 pgrid(G, PS);
  k_pool1<<<pgrid, 128, 0, stream>>>(bufB, gstart, gend, psum, pmax);
  k_pool2mlp<<<G, 128, 0, stream>>>(psum, pmax, gstart, gend, Wf1, bf1, Wf2, bf2, (float*)d_out);
}